// Round 5
// baseline (1399.780 us; speedup 1.0000x reference)
//
#include <hip/hip_runtime.h>
#include <cstdint>

typedef unsigned int u32;
typedef unsigned long long u64;

#define BATCH 8
#define H 1024
#define W 1024
#define HW (H*W)
#define KTOP 2048
#define NBIN 8192
#define SELCAP 4096
#define CAP (1<<18)          // peaks list capacity per batch (expected ~50k)
#define SENT 0xFFFFFFFFu

// mega tile geometry
#define TTX 32
#define TTY 32
#define SRX 68               // staged input span (32 + 2*18)
#define SSTR 69              // f32 row stride (odd -> bank-shifted rows)
#define CRX 36               // conv region span (32 + 2*2)
#define CSTR 37              // f64 row stride

// ws layout (bytes)
#define OFF_MISC 0           // cnt[8]
#define OFF_LIST (1024*1024)
#define OFF_THR  (512*1024)  // thresh[8]

__device__ __forceinline__ u64 make_key(double val, int p) {
  u64 dbits = __double_as_longlong(val);
  return (dbits & ~0xFFFFFull) | (u64)((~(u32)p) & 0xFFFFFu);
}

// ---------------- mega kernel: stage -> f64 conv -> outputs + peak list ----------------
__global__ __launch_bounds__(256) void mega_kernel(
    const float* __restrict__ in, const float* __restrict__ wc,
    const float* __restrict__ wsw, float* __restrict__ out0,
    float* __restrict__ convr, u64* __restrict__ list, u32* __restrict__ cnt)
{
  __shared__ float sS[SRX][SSTR];
  __shared__ float sC[SRX][SSTR];
  __shared__ double dcv[CRX][CSTR];

  int b = blockIdx.z;
  int tx0 = blockIdx.x * TTX;
  int ty0 = blockIdx.y * TTY;
  const float* Sp = in + (size_t)b * 3 * HW;
  const float* Cp = Sp + HW;
  const float* Rp = Sp + 2 * HW;

  // ---- stage S,C with zero-filled halo (global span [ty0-18, ty0+49]) ----
  for (int idx = threadIdx.x; idx < SRX * SRX; idx += 256) {
    int r = idx / SRX, c = idx - r * SRX;
    int gy = ty0 - 18 + r, gx = tx0 - 18 + c;
    float vs = 0.f, vc = 0.f;
    if ((unsigned)gy < (unsigned)H && (unsigned)gx < (unsigned)W) {
      int g = gy * W + gx;
      vs = Sp[g];
      vc = Cp[g];
    }
    sS[r][c] = vs;
    sC[r][c] = vc;
  }
  __syncthreads();

  // ---- f64 conv at 36x36 region (tile + 2 halo); FMA order == reference path ----
  for (int idx = threadIdx.x; idx < CRX * CRX; idx += 256) {
    int cy = idx / CRX, cx = idx - cy * CRX;
    double resp = 0.0;
    #pragma unroll
    for (int di = 0; di < 3; ++di) {
      const int d = (di == 0) ? 1 : (di == 1) ? 4 : 16;
      double ac = 0.0, as = 0.0;
      #pragma unroll
      for (int ky = 0; ky < 3; ++ky) {
        int r = cy + 16 + (ky - 1) * d;
        #pragma unroll
        for (int kx = 0; kx < 3; ++kx) {
          int c = cx + 16 + (kx - 1) * d;
          double w_c = (double)wc[di * 9 + ky * 3 + kx];
          double w_s = (double)wsw[di * 9 + ky * 3 + kx];
          ac = fma((double)sC[r][c], w_c, ac);
          as = fma((double)sS[r][c], w_s, as);
        }
      }
      resp += ac;
      resp += as;
    }
    dcv[cy][cx] = resp > 0.0 ? resp : 0.0;
  }
  __syncthreads();

  // ---- pointwise outputs + peak test ----
  float* ob = out0 + (size_t)b * 3 * HW;
  float* cb = convr + (size_t)b * HW;
  for (int idx = threadIdx.x; idx < TTX * TTY; idx += 256) {
    int ly = idx >> 5, lx = idx & 31;
    int y = ty0 + ly, x = tx0 + lx;
    int p = y * W + x;

    ob[p] = sS[ly + 18][lx + 18];
    ob[HW + p] = sC[ly + 18][lx + 18];
    ob[2 * HW + p] = expf(Rp[p]) - 1.0f;

    double val = dcv[ly + 2][lx + 2];
    cb[p] = (float)val;

    if (y < 5 || y >= H - 5 || x < 5 || x >= W - 5) continue;

    double cs0[5], cs1[5], cs2[5];
    #pragma unroll
    for (int jc = 0; jc < 5; ++jc) {
      double v0 = dcv[ly + 0][lx + jc];
      double v1 = dcv[ly + 1][lx + jc];
      double v2 = dcv[ly + 2][lx + jc];
      double v3 = dcv[ly + 3][lx + jc];
      double v4 = dcv[ly + 4][lx + jc];
      cs0[jc] = v0 + v1 + v2;
      cs1[jc] = v1 + v2 + v3;
      cs2[jc] = v2 + v3 + v4;
    }

    double sc = (cs1[1] + cs1[2] + cs1[3]) * (1.0 / 9.0);
    if (!(sc > 0.1)) continue;

    bool pk = true;
    #pragma unroll
    for (int j = 0; j < 3; ++j) {
      pk = pk && (sc >= (cs0[j] + cs0[j + 1] + cs0[j + 2]) * (1.0 / 9.0));
      pk = pk && (sc >= (cs2[j] + cs2[j + 1] + cs2[j + 2]) * (1.0 / 9.0));
    }
    pk = pk && (sc >= (cs1[0] + cs1[1] + cs1[2]) * (1.0 / 9.0));
    pk = pk && (sc >= (cs1[2] + cs1[3] + cs1[4]) * (1.0 / 9.0));
    if (!pk) continue;

    if (!(val > 0.1)) continue;

    u64 k64 = make_key(val, p);
    u32 pos = atomicAdd(&cnt[b], 1u);
    if (pos < CAP) list[(size_t)b * CAP + pos] = k64;
  }
}

// ---------------- select: both radix levels + suffix scans, one block per batch ----------
__global__ __launch_bounds__(1024) void select_kernel(
    const u64* __restrict__ list, const u32* __restrict__ cnt, u32* __restrict__ thresh)
{
  __shared__ u32 sfx[NBIN];
  __shared__ u32 sh_t1, sh_ab;
  int b = blockIdx.x;
  int tid = threadIdx.x;
  int N = (int)cnt[b]; if (N > CAP) N = CAP;
  const u64* L = list + (size_t)b * CAP;

  // level-1 histogram
  #pragma unroll
  for (int k = 0; k < 8; ++k) sfx[tid * 8 + k] = 0;
  __syncthreads();
  for (int i = tid; i < N; i += 1024)
    atomicAdd(&sfx[(u32)((L[i] >> 51) & 0x1FFF)], 1u);
  __syncthreads();

  // suffix scan
  for (int off = 1; off < NBIN; off <<= 1) {
    u32 t[8];
    #pragma unroll
    for (int k = 0; k < 8; ++k) {
      int i = tid * 8 + k;
      t[k] = (i + off < NBIN) ? sfx[i + off] : 0u;
    }
    __syncthreads();
    #pragma unroll
    for (int k = 0; k < 8; ++k) sfx[tid * 8 + k] += t[k];
    __syncthreads();
  }

  u32 total = sfx[0];
  if (total <= KTOP) { if (tid == 0) thresh[b] = 0u; return; }

  #pragma unroll
  for (int k = 0; k < 8; ++k) {
    int i = tid * 8 + k;
    u32 s = sfx[i];
    u32 nxt = (i + 1 < NBIN) ? sfx[i + 1] : 0u;
    if (s >= KTOP && nxt < KTOP) { sh_t1 = (u32)i; sh_ab = nxt; }
  }
  __syncthreads();
  u32 t1 = sh_t1, ab = sh_ab;
  __syncthreads();

  // level-2 histogram
  #pragma unroll
  for (int k = 0; k < 8; ++k) sfx[tid * 8 + k] = 0;
  __syncthreads();
  for (int i = tid; i < N; i += 1024) {
    u64 kk = L[i];
    if ((u32)((kk >> 51) & 0x1FFF) == t1)
      atomicAdd(&sfx[(u32)((kk >> 38) & 0x1FFF)], 1u);
  }
  __syncthreads();

  for (int off = 1; off < NBIN; off <<= 1) {
    u32 t[8];
    #pragma unroll
    for (int k = 0; k < 8; ++k) {
      int i = tid * 8 + k;
      t[k] = (i + off < NBIN) ? sfx[i + off] : 0u;
    }
    __syncthreads();
    #pragma unroll
    for (int k = 0; k < 8; ++k) sfx[tid * 8 + k] += t[k];
    __syncthreads();
  }

  #pragma unroll
  for (int k = 0; k < 8; ++k) {
    int i = tid * 8 + k;
    u32 s = ab + sfx[i];
    u32 nxt = ab + ((i + 1 < NBIN) ? sfx[i + 1] : 0u);
    if (s >= KTOP && nxt < KTOP) thresh[b] = (t1 << 13) | (u32)i;
  }
}

// ---------------- sort_out: compact(list,thresh) -> LDS bitonic -> center_pred ----------
__global__ __launch_bounds__(1024) void sort_out_kernel(
    const u64* __restrict__ list, const u32* __restrict__ cnt,
    const u32* __restrict__ thresh, const float* __restrict__ convr,
    float* __restrict__ center)
{
  __shared__ u64 sk[SELCAP];
  __shared__ u32 scnt;
  int b = blockIdx.x;
  int tid = threadIdx.x;
  if (tid == 0) scnt = 0;
  for (int i = tid; i < SELCAP; i += 1024) sk[i] = 0ULL;
  __syncthreads();

  int N = (int)cnt[b]; if (N > CAP) N = CAP;
  u64 th = (u64)thresh[b];
  const u64* L = list + (size_t)b * CAP;
  for (int i = tid; i < N; i += 1024) {
    u64 k = L[i];
    if ((k >> 38) >= th) {
      u32 pos = atomicAdd(&scnt, 1u);
      if (pos < SELCAP) sk[pos] = k;
    }
  }
  __syncthreads();
  int M = (int)scnt; if (M > SELCAP) M = SELCAP;

  for (int k = 2; k <= SELCAP; k <<= 1) {
    for (int j = k >> 1; j > 0; j >>= 1) {
      __syncthreads();
      for (int i = tid; i < SELCAP; i += 1024) {
        int l = i ^ j;
        if (l > i) {
          u64 a = sk[i], bb = sk[l];
          bool up = ((i & k) == 0);
          bool sw = up ? (a < bb) : (a > bb);
          if (sw) { sk[i] = bb; sk[l] = a; }
        }
      }
    }
  }
  __syncthreads();

  for (int i = tid; i < KTOP; i += 1024) {
    float* o = center + ((size_t)b * KTOP + i) * 5;
    if (i < M) {
      u64 key = sk[i];
      u32 p = (~(u32)key) & 0xFFFFFu;
      float v = convr[(size_t)b * HW + p];
      o[0] = 1.0f;
      o[1] = (float)(p & (W - 1));
      o[2] = (float)(p >> 10);
      o[3] = v;
      o[4] = v;
    } else {
      o[0] = 0.f; o[1] = 0.f; o[2] = 0.f; o[3] = 0.f; o[4] = 0.f;
    }
  }
}

extern "C" void kernel_launch(void* const* d_in, const int* in_sizes, int n_in,
                              void* d_out, int out_size, void* d_ws, size_t ws_size,
                              hipStream_t stream) {
  const float* in  = (const float*)d_in[0];
  const float* wc  = (const float*)d_in[1];
  const float* wsw = (const float*)d_in[2];

  float* out0   = (float*)d_out;                     // (8,3,1024,1024)
  float* center = out0 + (size_t)BATCH * 3 * HW;     // (8,2048,5)
  float* convr  = center + (size_t)BATCH * KTOP * 5; // (8,1,1024,1024)

  char* w = (char*)d_ws;                             // requires ws >= 17.5 MB (observed >= 66 MB)
  u32* cnt    = (u32*)(w + OFF_MISC);
  u32* thresh = (u32*)(w + OFF_THR);
  u64* list   = (u64*)(w + OFF_LIST);

  hipMemsetAsync(cnt, 0, 8 * sizeof(u32), stream);

  mega_kernel<<<dim3(W / TTX, H / TTY, BATCH), 256, 0, stream>>>(
      in, wc, wsw, out0, convr, list, cnt);
  select_kernel<<<BATCH, 1024, 0, stream>>>(list, cnt, thresh);
  sort_out_kernel<<<BATCH, 1024, 0, stream>>>(list, cnt, thresh, convr, center);
}